// Round 10
// baseline (2359.534 us; speedup 1.0000x reference)
//
#include <hip/hip_runtime.h>

#define SEQ   784
#define PADT  16                    // front zero-pad rows (max dilation 16)
#define NROW  (PADT + 784)          // 800
#define NWAVE 16
#define BLK   (NWAVE * 64)          // 1024 threads; tiles = wave + 16*slot
#define LDS_BYTES (NROW * 32 * 2)   // 51,200 B -> 2 blocks/CU, 32 waves/CU
// LDS layout: H[row][32 ch] bf16, XOR-swizzled in 16B granules:
//   phys_short(r,c) = r*32 + (((c>>3) ^ ((r>>1)&3))<<3) + (c&7)
// ws layout (preprocessed by prep_kernel):
//   WA  short8 [L][rt][tp][lane]  @ 0       (81,920 B)  -- dilated conv frags, exp2-scaled
//   WR  short8 [L][rt][lane]      @ 81920   (20,480 B)  -- residual frags
//   BD  float  [L][64]            @ 102400  ( 2,560 B)  -- dilated bias, exp2-scaled

#define WS_WR_OFF 81920
#define WS_BD_OFF 102400
#define SC_TANH (-2.885390082f)     // -2*log2(e)
#define SC_SIGM (-1.442695041f)     // -log2(e)

typedef __attribute__((ext_vector_type(8))) short  short8;
typedef __attribute__((ext_vector_type(4))) float  float4v;
typedef __attribute__((ext_vector_type(2))) unsigned int uint2v;

// pack two f32 -> bf16x2 (RNE): HW instruction on gfx950, 5-op fallback otherwise
#if __has_builtin(__builtin_amdgcn_cvt_pk_bf16_f32)
typedef __attribute__((ext_vector_type(2))) __bf16 bf16x2;
__device__ __forceinline__ unsigned int pk_rne(float lo, float hi) {
    union { bf16x2 v; unsigned int u; } r;
    r.v = __builtin_amdgcn_cvt_pk_bf16_f32(lo, hi);   // elem0=lo (low 16b)
    return r.u;
}
#else
__device__ __forceinline__ unsigned int pk_rne(float lo, float hi) {
    unsigned int a = __float_as_uint(lo);
    unsigned int b = __float_as_uint(hi);
    a += 0x7fffu + ((a >> 16) & 1u);
    b += 0x7fffu + ((b >> 16) & 1u);
    return __builtin_amdgcn_perm(b, a, 0x07060302);  // [a.hi16 | b.hi16<<16]
}
#endif
__device__ __forceinline__ unsigned short f2bf(float f) {
    unsigned int a = __float_as_uint(f);
    a += 0x7fffu + ((a >> 16) & 1u);
    return (unsigned short)(a >> 16);
}
// inputs are PRE-SCALED exp2 arguments: a' = -2*log2e*z_tanh, b' = -log2e*z_sig
__device__ __forceinline__ float gate_fn(float a, float b) {
    a = __builtin_amdgcn_fmed3f(a, -40.f, 40.f);
    b = __builtin_amdgcn_fmed3f(b, -40.f, 40.f);
    float ta = __builtin_amdgcn_exp2f(a);   // e^{-2*z_tanh}
    float tb = __builtin_amdgcn_exp2f(b);   // e^{-z_sig}
    return (1.0f - ta) * __builtin_amdgcn_rcpf((1.0f + ta) * (1.0f + tb));
}

// ---- weight preprocessing: 10 blocks x 64 lanes, frag-order bf16 into ws ----
__global__ void __launch_bounds__(64) prep_kernel(
    const float* __restrict__ w_dil, const float* __restrict__ b_dil,
    const float* __restrict__ w_res, unsigned char* __restrict__ ws)
{
    const int L    = blockIdx.x;
    const int lane = threadIdx.x;
    const int m    = lane & 15;
    const int q    = lane >> 4;
    short8* WSA = (short8*)ws;
    short8* WSR = (short8*)(ws + WS_WR_OFF);
    float*  WSB = (float*)(ws + WS_BD_OFF);

    #pragma unroll
    for (int rt = 0; rt < 4; ++rt) {
        const float sc = (rt < 2) ? SC_TANH : SC_SIGM;
        const float4* wp = (const float4*)(w_dil + (((L * 64 + rt * 16 + m) * 32) + q * 8) * 2);
        float4 c0 = wp[0], c1 = wp[1], c2 = wp[2], c3 = wp[3];
        union { unsigned int i[4]; short8 v; } u0, u1;
        u0.i[0] = pk_rne(sc * c0.x, sc * c0.z); u0.i[1] = pk_rne(sc * c1.x, sc * c1.z);
        u0.i[2] = pk_rne(sc * c2.x, sc * c2.z); u0.i[3] = pk_rne(sc * c3.x, sc * c3.z);
        u1.i[0] = pk_rne(sc * c0.y, sc * c0.w); u1.i[1] = pk_rne(sc * c1.y, sc * c1.w);
        u1.i[2] = pk_rne(sc * c2.y, sc * c2.w); u1.i[3] = pk_rne(sc * c3.y, sc * c3.w);
        WSA[((L * 4 + rt) * 2 + 0) * 64 + lane] = u0.v;
        WSA[((L * 4 + rt) * 2 + 1) * 64 + lane] = u1.v;
    }
    #pragma unroll
    for (int rt = 0; rt < 2; ++rt) {
        const float4* wp = (const float4*)(w_res + (L * 32 + rt * 16 + m) * 32 + q * 8);
        float4 d0 = wp[0], d1 = wp[1];
        union { unsigned int i[4]; short8 v; } u;
        u.i[0] = pk_rne(d0.x, d0.y); u.i[1] = pk_rne(d0.z, d0.w);
        u.i[2] = pk_rne(d1.x, d1.y); u.i[3] = pk_rne(d1.z, d1.w);
        WSR[(L * 2 + rt) * 64 + lane] = u.v;
    }
    WSB[L * 64 + lane] = b_dil[L * 64 + lane] * ((lane < 32) ? SC_TANH : SC_SIGM);
}

__global__ void __launch_bounds__(BLK, 8) wavenet_kernel(
    const float* __restrict__ x,
    const float* __restrict__ w_causal,
    const float* __restrict__ b_causal,
    const float* __restrict__ b_res,
    const float* __restrict__ w_out,
    const float* __restrict__ b_out,
    const unsigned char* __restrict__ ws,
    float* __restrict__ out)
{
    extern __shared__ unsigned short lds[];
    unsigned short* H = lds;                    // [NROW][32] bf16, granule-swizzled

    const int tid = threadIdx.x;
    const int b   = blockIdx.x;

    // ---- zero pad rows (whole rows -> swizzle-agnostic) ----
    {
        unsigned int* p = (unsigned int*)H;
        if (tid < PADT * 16) p[tid] = 0u;
    }

    // ---- causal conv straight from global x ----
    {
        int o = tid & 31;                       // invariant under += BLK (1024%32==0)
        const int gsh = (o >> 3) << 3;          // granule base of o (shorts)
        const int oo  = o & 7;
        float wc0 = w_causal[o * 2 + 0];
        float wc1 = w_causal[o * 2 + 1];
        float bc  = b_causal[o];
        const float* xb = x + b * SEQ;
        for (int idx = tid; idx < SEQ * 32; idx += BLK) {
            int t = idx >> 5;
            float v = bc;
            if (t >= 2) v += wc0 * xb[t - 2];
            if (t >= 1) v += wc1 * xb[t - 1];
            int r = PADT + t;
            int sw = ((r >> 1) & 3) << 3;
            H[r * 32 + (gsh ^ sw) + oo] = f2bf(v);
        }
    }
    __syncthreads();

    const int lane = tid & 63;
    const int wave = tid >> 6;
    const int m    = lane & 15;   // A-row / B-col / D-col
    const int q    = lane >> 4;   // quad
    const int adr1 = (32 * (q & 1) + m) * 4;   // bpermute byte addrs (invariant)
    const int adr2 = adr1 + 64;
    const int hi   = q >> 1;
    const int rowu0 = PADT + wave * 16 + m;    // slot s -> rows rowu0 + s*256
    const int su    = (rowu0 >> 1) & 3;        // swizzle sel (slot-invariant: 256/2%4==0)
    // per-lane constant physical offsets within a row
    const int offBu = ((q ^ su) << 3);                         // B unshifted granule
    const int offH1 = (((q >> 1) ^ su) << 3) + 4 * (q & 1);    // h ch q*4..+3 (stores)
    const int offH2 = ((((q >> 1) + 2) ^ su) << 3) + 4 * (q & 1); // ch 16+q*4..+3

    // identity A-frags for the residual h-passthrough MFMA:
    //   I0[m][k=q*8+j] = (k == m),      I1[m][k] = (k == m+16)
    short8 I0, I1;
    #pragma unroll
    for (int j = 0; j < 8; ++j) {
        I0[j] = (q * 8 + j == m)      ? (short)0x3F80 : (short)0;
        I1[j] = (q * 8 + j == m + 16) ? (short)0x3F80 : (short)0;
    }

    const short8* WSA = (const short8*)ws;
    const short8* WSR = (const short8*)(ws + WS_WR_OFF);
    const float*  WSB = (const float*)(ws + WS_BD_OFF);

    const int dil[10] = {1, 2, 4, 8, 16, 1, 2, 4, 8, 16};

    for (int L = 0; L < 10; ++L) {
        const int d = dil[L];

        // ---- frags: straight loads, zero conversion VALU ----
        short8 WA[4][2], WR[2];
        #pragma unroll
        for (int rt = 0; rt < 4; ++rt) {
            WA[rt][0] = WSA[((L * 4 + rt) * 2 + 0) * 64 + lane];
            WA[rt][1] = WSA[((L * 4 + rt) * 2 + 1) * 64 + lane];
        }
        WR[0] = WSR[(L * 2 + 0) * 64 + lane];
        WR[1] = WSR[(L * 2 + 1) * 64 + lane];
        float4v BDv[4], BRv[2];
        #pragma unroll
        for (int rt = 0; rt < 4; ++rt)
            BDv[rt] = *(const float4v*)(WSB + L * 64 + rt * 16 + q * 4);
        #pragma unroll
        for (int rt = 0; rt < 2; ++rt) {
            const float* bp = b_res + L * 32 + rt * 16 + q * 4;
            BRv[rt] = (float4v){bp[0], bp[1], bp[2], bp[3]};
        }
        // shifted-read swizzle (depends on d -> per layer)
        const int rs0   = rowu0 - d;
        const int offBs = ((q ^ ((rs0 >> 1) & 3)) << 3);

        auto do_tile = [&](int s, uint2v& n0, uint2v& n1) {
            const int rbase  = (rowu0 + s * (NWAVE * 16)) * 32;
            const int rbases = (rs0   + s * (NWAVE * 16)) * 32;
            const short8 Bs = *(const short8*)(H + rbases + offBs);
            const short8 Bu = *(const short8*)(H + rbase + offBu);

            // residual acc starts now: br + h (identity MFMA on the idle pipe)
            float4v r0 = BRv[0], r1 = BRv[1];
            r0 = __builtin_amdgcn_mfma_f32_16x16x32_bf16(I0, Bu, r0, 0, 0, 0);
            r1 = __builtin_amdgcn_mfma_f32_16x16x32_bf16(I1, Bu, r1, 0, 0, 0);

            float4v a0 = BDv[0], a1 = BDv[1], a2 = BDv[2], a3 = BDv[3];
            a0 = __builtin_amdgcn_mfma_f32_16x16x32_bf16(WA[0][0], Bs, a0, 0, 0, 0);
            a0 = __builtin_amdgcn_mfma_f32_16x16x32_bf16(WA[0][1], Bu, a0, 0, 0, 0);
            a1 = __builtin_amdgcn_mfma_f32_16x16x32_bf16(WA[1][0], Bs, a1, 0, 0, 0);
            a1 = __builtin_amdgcn_mfma_f32_16x16x32_bf16(WA[1][1], Bu, a1, 0, 0, 0);
            a2 = __builtin_amdgcn_mfma_f32_16x16x32_bf16(WA[2][0], Bs, a2, 0, 0, 0);
            a2 = __builtin_amdgcn_mfma_f32_16x16x32_bf16(WA[2][1], Bu, a2, 0, 0, 0);
            a3 = __builtin_amdgcn_mfma_f32_16x16x32_bf16(WA[3][0], Bs, a3, 0, 0, 0);
            a3 = __builtin_amdgcn_mfma_f32_16x16x32_bf16(WA[3][1], Bu, a3, 0, 0, 0);

            // acc already holds exp2 args (weights+bias pre-scaled)
            float g00 = gate_fn(a0[0], a2[0]), g01 = gate_fn(a0[1], a2[1]);
            float g02 = gate_fn(a0[2], a2[2]), g03 = gate_fn(a0[3], a2[3]);
            float g10 = gate_fn(a1[0], a3[0]), g11 = gate_fn(a1[1], a3[1]);
            float g12 = gate_fn(a1[2], a3[2]), g13 = gate_fn(a1[3], a3[3]);
            int P0 = (int)pk_rne(g00, g01), P1 = (int)pk_rne(g02, g03);
            int P2 = (int)pk_rne(g10, g11), P3 = (int)pk_rne(g12, g13);

            int A0 = __builtin_amdgcn_ds_bpermute(adr1, P0);
            int A1 = __builtin_amdgcn_ds_bpermute(adr1, P1);
            int A2 = __builtin_amdgcn_ds_bpermute(adr1, P2);
            int A3 = __builtin_amdgcn_ds_bpermute(adr1, P3);
            int C0 = __builtin_amdgcn_ds_bpermute(adr2, P0);
            int C1 = __builtin_amdgcn_ds_bpermute(adr2, P1);
            int C2 = __builtin_amdgcn_ds_bpermute(adr2, P2);
            int C3 = __builtin_amdgcn_ds_bpermute(adr2, P3);
            union { int i[4]; short8 v; } ug;
            ug.i[0] = hi ? A2 : A0; ug.i[1] = hi ? A3 : A1;
            ug.i[2] = hi ? C2 : C0; ug.i[3] = hi ? C3 : C1;
            const short8 Gf = ug.v;

            r0 = __builtin_amdgcn_mfma_f32_16x16x32_bf16(WR[0], Gf, r0, 0, 0, 0);
            r1 = __builtin_amdgcn_mfma_f32_16x16x32_bf16(WR[1], Gf, r1, 0, 0, 0);

            n0 = (uint2v){pk_rne(r0[0], r0[1]), pk_rne(r0[2], r0[3])};
            n1 = (uint2v){pk_rne(r1[0], r1[1]), pk_rne(r1[2], r1[3])};
        };
        auto store_tile = [&](int s, const uint2v& n0, const uint2v& n1) {
            const int rbase = (rowu0 + s * (NWAVE * 16)) * 32;
            *(uint2v*)(H + rbase + offH1) = n0;
            *(uint2v*)(H + rbase + offH2) = n1;
        };

        // In-place update, descending two-pass. Tiles = wave + 16*slot.
        // Pass A: slots 2..3 (tiles 32..48, rows >= 528); pass B: slots 0..1
        // (tiles 0..31, all reads from rows <= 527) -> storeA can overlap
        // computeB with no barrier (disjoint row ranges, checked per-tile).
        uint2v A0v[2], A1v[2], B0v[2], B1v[2];
        do_tile(2, A0v[0], A1v[0]);
        if (wave == 0) do_tile(3, A0v[1], A1v[1]);   // tile 48 (wave-uniform branch)
        __syncthreads();                         // pass-A reads done
        store_tile(2, A0v[0], A1v[0]);
        if (wave == 0) store_tile(3, A0v[1], A1v[1]);
        // no barrier: pass-B reads never touch pass-A rows
        do_tile(0, B0v[0], B1v[0]);
        do_tile(1, B0v[1], B1v[1]);
        __syncthreads();                         // pass-B reads + pass-A writes done
        store_tile(0, B0v[0], B1v[0]);
        store_tile(1, B0v[1], B1v[1]);
        __syncthreads();                         // writes visible for next layer
    }

    // ---- output proj ----
    {
        float wo[32];
        #pragma unroll
        for (int k = 0; k < 32; ++k) wo[k] = w_out[k];
        float bo = b_out[0];
        for (int t = tid; t < SEQ; t += BLK) {
            int r = PADT + t;
            int sw = ((r >> 1) & 3) << 3;
            const unsigned short* hp = H + r * 32;
            float s = bo;
            #pragma unroll
            for (int kk = 0; kk < 32; kk += 4) {
                int c = ((((kk >> 3) << 3) ^ sw)) + (kk & 7);
                uint2v hh = *(const uint2v*)(hp + c);
                s += wo[kk]     * __uint_as_float(hh.x << 16);
                s += wo[kk + 1] * __uint_as_float(hh.x & 0xffff0000u);
                s += wo[kk + 2] * __uint_as_float(hh.y << 16);
                s += wo[kk + 3] * __uint_as_float(hh.y & 0xffff0000u);
            }
            out[b * SEQ + t] = s;
        }
    }
}

extern "C" void kernel_launch(void* const* d_in, const int* in_sizes, int n_in,
                              void* d_out, int out_size, void* d_ws, size_t ws_size,
                              hipStream_t stream) {
    const float* x        = (const float*)d_in[0];
    const float* w_causal = (const float*)d_in[1];
    const float* b_causal = (const float*)d_in[2];
    const float* w_dil    = (const float*)d_in[3];
    const float* b_dil    = (const float*)d_in[4];
    const float* w_res    = (const float*)d_in[5];
    const float* b_res    = (const float*)d_in[6];
    const float* w_out    = (const float*)d_in[7];
    const float* b_out    = (const float*)d_in[8];
    float* out = (float*)d_out;
    unsigned char* ws = (unsigned char*)d_ws;

    const int B = in_sizes[0] / SEQ;  // 2048

    prep_kernel<<<10, 64, 0, stream>>>(w_dil, b_dil, w_res, ws);
    wavenet_kernel<<<B, BLK, LDS_BYTES, stream>>>(
        x, w_causal, b_causal, b_res, w_out, b_out, ws, out);
}

// Round 11
// 1841.237 us; speedup vs baseline: 1.2815x; 1.2815x over previous
//
#include <hip/hip_runtime.h>

#define SEQ   784
#define PADT  16                    // front zero-pad rows (max dilation 16)
#define NROW  (PADT + 784)          // 800
#define NWAVE 12
#define BLK   (NWAVE * 64)          // 768 threads; tiles = wave + 12*slot, 49 = 12*4+1
#define LDS_BYTES (NROW * 32 * 2)   // 51,200 B -> 2 blocks/CU, 24 waves/CU
// LDS layout: H[row][32 ch] bf16, XOR-swizzled in 16B granules:
//   phys_short(r,c) = r*32 + (((c>>3) ^ ((r>>1)&3))<<3) + (c&7)
// ws layout (preprocessed by prep_kernel):
//   WA  short8 [L][rt][tp][lane]  @ 0       (81,920 B)  -- dilated conv frags, exp2-scaled
//   WR  short8 [L][rt][lane]      @ 81920   (20,480 B)  -- residual frags
//   BD  float  [L][64]            @ 102400  ( 2,560 B)  -- dilated bias, exp2-scaled

#define WS_WR_OFF 81920
#define WS_BD_OFF 102400
#define SC_TANH (-2.885390082f)     // -2*log2(e)
#define SC_SIGM (-1.442695041f)     // -log2(e)

typedef __attribute__((ext_vector_type(8))) short  short8;
typedef __attribute__((ext_vector_type(4))) float  float4v;
typedef __attribute__((ext_vector_type(2))) unsigned int uint2v;

// pack two f32 -> bf16x2 (RNE): HW instruction on gfx950, 5-op fallback otherwise
#if __has_builtin(__builtin_amdgcn_cvt_pk_bf16_f32)
typedef __attribute__((ext_vector_type(2))) __bf16 bf16x2;
__device__ __forceinline__ unsigned int pk_rne(float lo, float hi) {
    union { bf16x2 v; unsigned int u; } r;
    r.v = __builtin_amdgcn_cvt_pk_bf16_f32(lo, hi);   // elem0=lo (low 16b)
    return r.u;
}
#else
__device__ __forceinline__ unsigned int pk_rne(float lo, float hi) {
    unsigned int a = __float_as_uint(lo);
    unsigned int b = __float_as_uint(hi);
    a += 0x7fffu + ((a >> 16) & 1u);
    b += 0x7fffu + ((b >> 16) & 1u);
    return __builtin_amdgcn_perm(b, a, 0x07060302);  // [a.hi16 | b.hi16<<16]
}
#endif
__device__ __forceinline__ unsigned short f2bf(float f) {
    unsigned int a = __float_as_uint(f);
    a += 0x7fffu + ((a >> 16) & 1u);
    return (unsigned short)(a >> 16);
}
// inputs are PRE-SCALED exp2 arguments: a' = -2*log2e*z_tanh, b' = -log2e*z_sig
__device__ __forceinline__ float gate_fn(float a, float b) {
    a = __builtin_amdgcn_fmed3f(a, -40.f, 40.f);
    b = __builtin_amdgcn_fmed3f(b, -40.f, 40.f);
    float ta = __builtin_amdgcn_exp2f(a);   // e^{-2*z_tanh}
    float tb = __builtin_amdgcn_exp2f(b);   // e^{-z_sig}
    return (1.0f - ta) * __builtin_amdgcn_rcpf((1.0f + ta) * (1.0f + tb));
}

// ---- weight preprocessing: 10 blocks x 64 lanes, frag-order bf16 into ws ----
__global__ void __launch_bounds__(64) prep_kernel(
    const float* __restrict__ w_dil, const float* __restrict__ b_dil,
    const float* __restrict__ w_res, unsigned char* __restrict__ ws)
{
    const int L    = blockIdx.x;
    const int lane = threadIdx.x;
    const int m    = lane & 15;
    const int q    = lane >> 4;
    short8* WSA = (short8*)ws;
    short8* WSR = (short8*)(ws + WS_WR_OFF);
    float*  WSB = (float*)(ws + WS_BD_OFF);

    #pragma unroll
    for (int rt = 0; rt < 4; ++rt) {
        const float sc = (rt < 2) ? SC_TANH : SC_SIGM;
        const float4* wp = (const float4*)(w_dil + (((L * 64 + rt * 16 + m) * 32) + q * 8) * 2);
        float4 c0 = wp[0], c1 = wp[1], c2 = wp[2], c3 = wp[3];
        union { unsigned int i[4]; short8 v; } u0, u1;
        u0.i[0] = pk_rne(sc * c0.x, sc * c0.z); u0.i[1] = pk_rne(sc * c1.x, sc * c1.z);
        u0.i[2] = pk_rne(sc * c2.x, sc * c2.z); u0.i[3] = pk_rne(sc * c3.x, sc * c3.z);
        u1.i[0] = pk_rne(sc * c0.y, sc * c0.w); u1.i[1] = pk_rne(sc * c1.y, sc * c1.w);
        u1.i[2] = pk_rne(sc * c2.y, sc * c2.w); u1.i[3] = pk_rne(sc * c3.y, sc * c3.w);
        WSA[((L * 4 + rt) * 2 + 0) * 64 + lane] = u0.v;
        WSA[((L * 4 + rt) * 2 + 1) * 64 + lane] = u1.v;
    }
    #pragma unroll
    for (int rt = 0; rt < 2; ++rt) {
        const float4* wp = (const float4*)(w_res + (L * 32 + rt * 16 + m) * 32 + q * 8);
        float4 d0 = wp[0], d1 = wp[1];
        union { unsigned int i[4]; short8 v; } u;
        u.i[0] = pk_rne(d0.x, d0.y); u.i[1] = pk_rne(d0.z, d0.w);
        u.i[2] = pk_rne(d1.x, d1.y); u.i[3] = pk_rne(d1.z, d1.w);
        WSR[(L * 2 + rt) * 64 + lane] = u.v;
    }
    WSB[L * 64 + lane] = b_dil[L * 64 + lane] * ((lane < 32) ? SC_TANH : SC_SIGM);
}

__global__ void __launch_bounds__(BLK, 6) wavenet_kernel(
    const float* __restrict__ x,
    const float* __restrict__ w_causal,
    const float* __restrict__ b_causal,
    const float* __restrict__ b_res,
    const float* __restrict__ w_out,
    const float* __restrict__ b_out,
    const unsigned char* __restrict__ ws,
    float* __restrict__ out)
{
    extern __shared__ unsigned short lds[];
    unsigned short* H = lds;                    // [NROW][32] bf16, granule-swizzled

    const int tid = threadIdx.x;
    const int b   = blockIdx.x;

    // ---- zero pad rows (whole rows -> swizzle-agnostic) ----
    {
        unsigned int* p = (unsigned int*)H;
        if (tid < PADT * 16) p[tid] = 0u;
    }

    // ---- causal conv straight from global x ----
    {
        int o = tid & 31;                       // invariant under += BLK (768%32==0)
        const int gsh = (o >> 3) << 3;          // granule base of o (shorts)
        const int oo  = o & 7;
        float wc0 = w_causal[o * 2 + 0];
        float wc1 = w_causal[o * 2 + 1];
        float bc  = b_causal[o];
        const float* xb = x + b * SEQ;
        for (int idx = tid; idx < SEQ * 32; idx += BLK) {
            int t = idx >> 5;
            float v = bc;
            if (t >= 2) v += wc0 * xb[t - 2];
            if (t >= 1) v += wc1 * xb[t - 1];
            int r = PADT + t;
            int sw = ((r >> 1) & 3) << 3;
            H[r * 32 + (gsh ^ sw) + oo] = f2bf(v);
        }
    }
    __syncthreads();

    const int lane = tid & 63;
    const int wave = tid >> 6;
    const int m    = lane & 15;   // A-row / B-col / D-col
    const int q    = lane >> 4;   // quad
    const int adr1 = (32 * (q & 1) + m) * 4;   // bpermute byte addrs (invariant)
    const int adr2 = adr1 + 64;
    const int hi   = q >> 1;
    const int rowu0 = PADT + wave * 16 + m;    // slot s -> rows rowu0 + s*192
    const int su    = (rowu0 >> 1) & 3;        // swizzle sel (slot-invariant: 192/2%4==0)
    // per-lane constant physical offsets within a row
    const int offBu = ((q ^ su) << 3);                         // B unshifted granule
    const int offH1 = (((q >> 1) ^ su) << 3) + 4 * (q & 1);    // h ch q*4..+3 (stores)
    const int offH2 = ((((q >> 1) + 2) ^ su) << 3) + 4 * (q & 1); // ch 16+q*4..+3

    // identity A-frags for the residual h-passthrough MFMA:
    //   I0[m][k=q*8+j] = (k == m),      I1[m][k] = (k == m+16)
    short8 I0, I1;
    #pragma unroll
    for (int j = 0; j < 8; ++j) {
        I0[j] = (q * 8 + j == m)      ? (short)0x3F80 : (short)0;
        I1[j] = (q * 8 + j == m + 16) ? (short)0x3F80 : (short)0;
    }

    const short8* WSA = (const short8*)ws;
    const short8* WSR = (const short8*)(ws + WS_WR_OFF);
    const float*  WSB = (const float*)(ws + WS_BD_OFF);

    const int dil[10] = {1, 2, 4, 8, 16, 1, 2, 4, 8, 16};

    for (int L = 0; L < 10; ++L) {
        const int d = dil[L];

        // ---- frags: straight loads, zero conversion VALU ----
        short8 WA[4][2], WR[2];
        #pragma unroll
        for (int rt = 0; rt < 4; ++rt) {
            WA[rt][0] = WSA[((L * 4 + rt) * 2 + 0) * 64 + lane];
            WA[rt][1] = WSA[((L * 4 + rt) * 2 + 1) * 64 + lane];
        }
        WR[0] = WSR[(L * 2 + 0) * 64 + lane];
        WR[1] = WSR[(L * 2 + 1) * 64 + lane];
        float4v BDv[4], BRv[2];
        #pragma unroll
        for (int rt = 0; rt < 4; ++rt)
            BDv[rt] = *(const float4v*)(WSB + L * 64 + rt * 16 + q * 4);
        #pragma unroll
        for (int rt = 0; rt < 2; ++rt) {
            const float* bp = b_res + L * 32 + rt * 16 + q * 4;
            BRv[rt] = (float4v){bp[0], bp[1], bp[2], bp[3]};
        }
        // shifted-read swizzle (depends on d -> per layer)
        const int rs0   = rowu0 - d;
        const int offBs = ((q ^ ((rs0 >> 1) & 3)) << 3);

        auto do_tile = [&](int s, uint2v& n0, uint2v& n1) {
            const int rbase  = (rowu0 + s * (NWAVE * 16)) * 32;
            const int rbases = (rs0   + s * (NWAVE * 16)) * 32;
            const short8 Bs = *(const short8*)(H + rbases + offBs);
            const short8 Bu = *(const short8*)(H + rbase + offBu);

            // residual acc starts now: br + h (identity MFMA on the idle pipe)
            float4v r0 = BRv[0], r1 = BRv[1];
            r0 = __builtin_amdgcn_mfma_f32_16x16x32_bf16(I0, Bu, r0, 0, 0, 0);
            r1 = __builtin_amdgcn_mfma_f32_16x16x32_bf16(I1, Bu, r1, 0, 0, 0);

            float4v a0 = BDv[0], a1 = BDv[1], a2 = BDv[2], a3 = BDv[3];
            a0 = __builtin_amdgcn_mfma_f32_16x16x32_bf16(WA[0][0], Bs, a0, 0, 0, 0);
            a0 = __builtin_amdgcn_mfma_f32_16x16x32_bf16(WA[0][1], Bu, a0, 0, 0, 0);
            a1 = __builtin_amdgcn_mfma_f32_16x16x32_bf16(WA[1][0], Bs, a1, 0, 0, 0);
            a1 = __builtin_amdgcn_mfma_f32_16x16x32_bf16(WA[1][1], Bu, a1, 0, 0, 0);
            a2 = __builtin_amdgcn_mfma_f32_16x16x32_bf16(WA[2][0], Bs, a2, 0, 0, 0);
            a2 = __builtin_amdgcn_mfma_f32_16x16x32_bf16(WA[2][1], Bu, a2, 0, 0, 0);
            a3 = __builtin_amdgcn_mfma_f32_16x16x32_bf16(WA[3][0], Bs, a3, 0, 0, 0);
            a3 = __builtin_amdgcn_mfma_f32_16x16x32_bf16(WA[3][1], Bu, a3, 0, 0, 0);

            // acc already holds exp2 args (weights+bias pre-scaled)
            float g00 = gate_fn(a0[0], a2[0]), g01 = gate_fn(a0[1], a2[1]);
            float g02 = gate_fn(a0[2], a2[2]), g03 = gate_fn(a0[3], a2[3]);
            float g10 = gate_fn(a1[0], a3[0]), g11 = gate_fn(a1[1], a3[1]);
            float g12 = gate_fn(a1[2], a3[2]), g13 = gate_fn(a1[3], a3[3]);
            int P0 = (int)pk_rne(g00, g01), P1 = (int)pk_rne(g02, g03);
            int P2 = (int)pk_rne(g10, g11), P3 = (int)pk_rne(g12, g13);

            int A0 = __builtin_amdgcn_ds_bpermute(adr1, P0);
            int A1 = __builtin_amdgcn_ds_bpermute(adr1, P1);
            int A2 = __builtin_amdgcn_ds_bpermute(adr1, P2);
            int A3 = __builtin_amdgcn_ds_bpermute(adr1, P3);
            int C0 = __builtin_amdgcn_ds_bpermute(adr2, P0);
            int C1 = __builtin_amdgcn_ds_bpermute(adr2, P1);
            int C2 = __builtin_amdgcn_ds_bpermute(adr2, P2);
            int C3 = __builtin_amdgcn_ds_bpermute(adr2, P3);
            union { int i[4]; short8 v; } ug;
            ug.i[0] = hi ? A2 : A0; ug.i[1] = hi ? A3 : A1;
            ug.i[2] = hi ? C2 : C0; ug.i[3] = hi ? C3 : C1;
            const short8 Gf = ug.v;

            r0 = __builtin_amdgcn_mfma_f32_16x16x32_bf16(WR[0], Gf, r0, 0, 0, 0);
            r1 = __builtin_amdgcn_mfma_f32_16x16x32_bf16(WR[1], Gf, r1, 0, 0, 0);

            n0 = (uint2v){pk_rne(r0[0], r0[1]), pk_rne(r0[2], r0[3])};
            n1 = (uint2v){pk_rne(r1[0], r1[1]), pk_rne(r1[2], r1[3])};
        };
        auto store_tile = [&](int s, const uint2v& n0, const uint2v& n1) {
            const int rbase = (rowu0 + s * (NWAVE * 16)) * 32;
            *(uint2v*)(H + rbase + offH1) = n0;
            *(uint2v*)(H + rbase + offH2) = n1;
        };

        // In-place update, descending two-pass. Tiles = wave + 12*slot.
        // Pass A: slots 2..4 (tiles 24..48, writes rows >= 400); pass B: slots
        // 0..1 (tiles 0..23, all reads from rows <= 399) -> storeA overlaps
        // computeB with no barrier (disjoint row ranges).
        uint2v A0v[3], A1v[3], B0v[2], B1v[2];
        do_tile(2, A0v[0], A1v[0]);
        do_tile(3, A0v[1], A1v[1]);
        if (wave == 0) do_tile(4, A0v[2], A1v[2]);   // tile 48 (wave-uniform branch)
        __syncthreads();                         // pass-A reads done
        store_tile(2, A0v[0], A1v[0]);
        store_tile(3, A0v[1], A1v[1]);
        if (wave == 0) store_tile(4, A0v[2], A1v[2]);
        // no barrier: pass-B reads never touch pass-A rows
        do_tile(0, B0v[0], B1v[0]);
        do_tile(1, B0v[1], B1v[1]);
        __syncthreads();                         // pass-B reads + pass-A writes done
        store_tile(0, B0v[0], B1v[0]);
        store_tile(1, B0v[1], B1v[1]);
        __syncthreads();                         // writes visible for next layer
    }

    // ---- output proj ----
    {
        float wo[32];
        #pragma unroll
        for (int k = 0; k < 32; ++k) wo[k] = w_out[k];
        float bo = b_out[0];
        for (int t = tid; t < SEQ; t += BLK) {
            int r = PADT + t;
            int sw = ((r >> 1) & 3) << 3;
            const unsigned short* hp = H + r * 32;
            float s = bo;
            #pragma unroll
            for (int kk = 0; kk < 32; kk += 4) {
                int c = ((((kk >> 3) << 3) ^ sw)) + (kk & 7);
                uint2v hh = *(const uint2v*)(hp + c);
                s += wo[kk]     * __uint_as_float(hh.x << 16);
                s += wo[kk + 1] * __uint_as_float(hh.x & 0xffff0000u);
                s += wo[kk + 2] * __uint_as_float(hh.y << 16);
                s += wo[kk + 3] * __uint_as_float(hh.y & 0xffff0000u);
            }
            out[b * SEQ + t] = s;
        }
    }
}

extern "C" void kernel_launch(void* const* d_in, const int* in_sizes, int n_in,
                              void* d_out, int out_size, void* d_ws, size_t ws_size,
                              hipStream_t stream) {
    const float* x        = (const float*)d_in[0];
    const float* w_causal = (const float*)d_in[1];
    const float* b_causal = (const float*)d_in[2];
    const float* w_dil    = (const float*)d_in[3];
    const float* b_dil    = (const float*)d_in[4];
    const float* w_res    = (const float*)d_in[5];
    const float* b_res    = (const float*)d_in[6];
    const float* w_out    = (const float*)d_in[7];
    const float* b_out    = (const float*)d_in[8];
    float* out = (float*)d_out;
    unsigned char* ws = (unsigned char*)d_ws;

    const int B = in_sizes[0] / SEQ;  // 2048

    prep_kernel<<<10, 64, 0, stream>>>(w_dil, b_dil, w_res, ws);
    wavenet_kernel<<<B, BLK, LDS_BYTES, stream>>>(
        x, w_causal, b_causal, b_res, w_out, b_out, ws, out);
}

// Round 12
// 479.747 us; speedup vs baseline: 4.9183x; 3.8379x over previous
//
#include <hip/hip_runtime.h>

#define SEQ   784
#define PADT  16                    // front zero-pad rows (max dilation 16)
#define NROW  (PADT + 784)          // 800
#define NWAVE 8
#define BLK   (NWAVE * 64)          // 512 threads; tiles = wave + 8*slot, 49 = 8*6+1
#define LDS_BYTES (NROW * 32 * 2)   // 51,200 B -> 2 blocks/CU, 16 waves/CU
// LDS layout: H[row][32 ch] bf16, XOR-swizzled in 16B granules:
//   phys_short(r,c) = r*32 + (((c>>3) ^ ((r>>1)&3))<<3) + (c&7)
// ws layout (preprocessed by prep_kernel):
//   WA  short8 [L][rt][tp][lane]  @ 0       (81,920 B)  -- dilated conv frags, exp2-scaled
//   WR  short8 [L][rt][lane]      @ 81920   (20,480 B)  -- residual frags
//   BD  float  [L][64]            @ 102400  ( 2,560 B)  -- dilated bias, exp2-scaled

#define WS_WR_OFF 81920
#define WS_BD_OFF 102400
#define SC_TANH (-2.885390082f)     // -2*log2(e)
#define SC_SIGM (-1.442695041f)     // -log2(e)

typedef __attribute__((ext_vector_type(8))) short  short8;
typedef __attribute__((ext_vector_type(4))) float  float4v;
typedef __attribute__((ext_vector_type(2))) unsigned int uint2v;

// pack two f32 -> bf16x2 (RNE): HW instruction on gfx950, 5-op fallback otherwise
#if __has_builtin(__builtin_amdgcn_cvt_pk_bf16_f32)
typedef __attribute__((ext_vector_type(2))) __bf16 bf16x2;
__device__ __forceinline__ unsigned int pk_rne(float lo, float hi) {
    union { bf16x2 v; unsigned int u; } r;
    r.v = __builtin_amdgcn_cvt_pk_bf16_f32(lo, hi);   // elem0=lo (low 16b)
    return r.u;
}
#else
__device__ __forceinline__ unsigned int pk_rne(float lo, float hi) {
    unsigned int a = __float_as_uint(lo);
    unsigned int b = __float_as_uint(hi);
    a += 0x7fffu + ((a >> 16) & 1u);
    b += 0x7fffu + ((b >> 16) & 1u);
    return __builtin_amdgcn_perm(b, a, 0x07060302);  // [a.hi16 | b.hi16<<16]
}
#endif
__device__ __forceinline__ unsigned short f2bf(float f) {
    unsigned int a = __float_as_uint(f);
    a += 0x7fffu + ((a >> 16) & 1u);
    return (unsigned short)(a >> 16);
}
// Two gates sharing one reciprocal. Inputs are PRE-SCALED exp2 args
// (a = -2log2e*z_tanh, b = -log2e*z_sig). Clamp +-30 bounds the 4-term
// product by 2^120 < FLT_MAX (no overflow possible); rcp error ~1ulp.
__device__ __forceinline__ void gate_pair(float a1, float b1, float a2, float b2,
                                          float& g1, float& g2) {
    a1 = __builtin_amdgcn_fmed3f(a1, -30.f, 30.f);
    b1 = __builtin_amdgcn_fmed3f(b1, -30.f, 30.f);
    a2 = __builtin_amdgcn_fmed3f(a2, -30.f, 30.f);
    b2 = __builtin_amdgcn_fmed3f(b2, -30.f, 30.f);
    float ta1 = __builtin_amdgcn_exp2f(a1), tb1 = __builtin_amdgcn_exp2f(b1);
    float ta2 = __builtin_amdgcn_exp2f(a2), tb2 = __builtin_amdgcn_exp2f(b2);
    float p1 = (1.0f + ta1) * (1.0f + tb1);
    float p2 = (1.0f + ta2) * (1.0f + tb2);
    float r  = __builtin_amdgcn_rcpf(p1 * p2);
    g1 = (1.0f - ta1) * p2 * r;
    g2 = (1.0f - ta2) * p1 * r;
}

// ---- weight preprocessing: 10 blocks x 64 lanes, frag-order bf16 into ws ----
__global__ void __launch_bounds__(64) prep_kernel(
    const float* __restrict__ w_dil, const float* __restrict__ b_dil,
    const float* __restrict__ w_res, unsigned char* __restrict__ ws)
{
    const int L    = blockIdx.x;
    const int lane = threadIdx.x;
    const int m    = lane & 15;
    const int q    = lane >> 4;
    short8* WSA = (short8*)ws;
    short8* WSR = (short8*)(ws + WS_WR_OFF);
    float*  WSB = (float*)(ws + WS_BD_OFF);

    #pragma unroll
    for (int rt = 0; rt < 4; ++rt) {
        const float sc = (rt < 2) ? SC_TANH : SC_SIGM;
        const float4* wp = (const float4*)(w_dil + (((L * 64 + rt * 16 + m) * 32) + q * 8) * 2);
        float4 c0 = wp[0], c1 = wp[1], c2 = wp[2], c3 = wp[3];
        union { unsigned int i[4]; short8 v; } u0, u1;
        u0.i[0] = pk_rne(sc * c0.x, sc * c0.z); u0.i[1] = pk_rne(sc * c1.x, sc * c1.z);
        u0.i[2] = pk_rne(sc * c2.x, sc * c2.z); u0.i[3] = pk_rne(sc * c3.x, sc * c3.z);
        u1.i[0] = pk_rne(sc * c0.y, sc * c0.w); u1.i[1] = pk_rne(sc * c1.y, sc * c1.w);
        u1.i[2] = pk_rne(sc * c2.y, sc * c2.w); u1.i[3] = pk_rne(sc * c3.y, sc * c3.w);
        WSA[((L * 4 + rt) * 2 + 0) * 64 + lane] = u0.v;
        WSA[((L * 4 + rt) * 2 + 1) * 64 + lane] = u1.v;
    }
    #pragma unroll
    for (int rt = 0; rt < 2; ++rt) {
        const float4* wp = (const float4*)(w_res + (L * 32 + rt * 16 + m) * 32 + q * 8);
        float4 d0 = wp[0], d1 = wp[1];
        union { unsigned int i[4]; short8 v; } u;
        u.i[0] = pk_rne(d0.x, d0.y); u.i[1] = pk_rne(d0.z, d0.w);
        u.i[2] = pk_rne(d1.x, d1.y); u.i[3] = pk_rne(d1.z, d1.w);
        WSR[(L * 2 + rt) * 64 + lane] = u.v;
    }
    WSB[L * 64 + lane] = b_dil[L * 64 + lane] * ((lane < 32) ? SC_TANH : SC_SIGM);
}

__global__ void __launch_bounds__(BLK, 4) wavenet_kernel(
    const float* __restrict__ x,
    const float* __restrict__ w_causal,
    const float* __restrict__ b_causal,
    const float* __restrict__ b_res,
    const float* __restrict__ w_out,
    const float* __restrict__ b_out,
    const unsigned char* __restrict__ ws,
    float* __restrict__ out)
{
    extern __shared__ unsigned short lds[];
    unsigned short* H = lds;                    // [NROW][32] bf16, granule-swizzled

    const int tid = threadIdx.x;
    const int b   = blockIdx.x;

    // ---- zero pad rows (whole rows -> swizzle-agnostic) ----
    {
        unsigned int* p = (unsigned int*)H;
        if (tid < PADT * 16) p[tid] = 0u;
    }

    // ---- causal conv straight from global x ----
    {
        int o = tid & 31;                       // invariant under += BLK (512%32==0)
        const int gsh = (o >> 3) << 3;          // granule base of o (shorts)
        const int oo  = o & 7;
        float wc0 = w_causal[o * 2 + 0];
        float wc1 = w_causal[o * 2 + 1];
        float bc  = b_causal[o];
        const float* xb = x + b * SEQ;
        for (int idx = tid; idx < SEQ * 32; idx += BLK) {
            int t = idx >> 5;
            float v = bc;
            if (t >= 2) v += wc0 * xb[t - 2];
            if (t >= 1) v += wc1 * xb[t - 1];
            int r = PADT + t;
            int sw = ((r >> 1) & 3) << 3;
            H[r * 32 + (gsh ^ sw) + oo] = f2bf(v);
        }
    }
    __syncthreads();

    const int lane = tid & 63;
    const int wave = tid >> 6;
    const int m    = lane & 15;   // A-row / B-col / D-col
    const int q    = lane >> 4;   // quad
    const int adr1 = (32 * (q & 1) + m) * 4;   // bpermute byte addrs (invariant)
    const int adr2 = adr1 + 64;
    const int hi   = q >> 1;
    const int rowu0 = PADT + wave * 16 + m;    // slot s -> rows rowu0 + s*128
    const int su    = (rowu0 >> 1) & 3;        // swizzle sel (slot-invariant: 128/2%4==0)
    // per-lane constant physical offsets within a row
    const int offBu = ((q ^ su) << 3);                         // B unshifted granule
    const int offH1 = (((q >> 1) ^ su) << 3) + 4 * (q & 1);    // h ch q*4..+3 (stores)
    const int offH2 = ((((q >> 1) + 2) ^ su) << 3) + 4 * (q & 1); // ch 16+q*4..+3

    // identity A-frags for the residual h-passthrough MFMA:
    //   I0[m][k=q*8+j] = (k == m),      I1[m][k] = (k == m+16)
    short8 I0, I1;
    #pragma unroll
    for (int j = 0; j < 8; ++j) {
        I0[j] = (q * 8 + j == m)      ? (short)0x3F80 : (short)0;
        I1[j] = (q * 8 + j == m + 16) ? (short)0x3F80 : (short)0;
    }

    const short8* WSA = (const short8*)ws;
    const short8* WSR = (const short8*)(ws + WS_WR_OFF);
    const float*  WSB = (const float*)(ws + WS_BD_OFF);

    const int dil[10] = {1, 2, 4, 8, 16, 1, 2, 4, 8, 16};

    for (int L = 0; L < 10; ++L) {
        const int d = dil[L];

        // ---- frags: straight loads, zero conversion VALU ----
        short8 WA[4][2], WR[2];
        #pragma unroll
        for (int rt = 0; rt < 4; ++rt) {
            WA[rt][0] = WSA[((L * 4 + rt) * 2 + 0) * 64 + lane];
            WA[rt][1] = WSA[((L * 4 + rt) * 2 + 1) * 64 + lane];
        }
        WR[0] = WSR[(L * 2 + 0) * 64 + lane];
        WR[1] = WSR[(L * 2 + 1) * 64 + lane];
        float4v BDv[4], BRv[2];
        #pragma unroll
        for (int rt = 0; rt < 4; ++rt)
            BDv[rt] = *(const float4v*)(WSB + L * 64 + rt * 16 + q * 4);
        #pragma unroll
        for (int rt = 0; rt < 2; ++rt) {
            const float* bp = b_res + L * 32 + rt * 16 + q * 4;
            BRv[rt] = (float4v){bp[0], bp[1], bp[2], bp[3]};
        }
        // shifted-read swizzle (depends on d -> per layer)
        const int rs0   = rowu0 - d;
        const int offBs = ((q ^ ((rs0 >> 1) & 3)) << 3);

        auto do_tile = [&](int s, uint2v& n0, uint2v& n1) {
            const int rbase  = (rowu0 + s * (NWAVE * 16)) * 32;
            const int rbases = (rs0   + s * (NWAVE * 16)) * 32;
            const short8 Bs = *(const short8*)(H + rbases + offBs);
            const short8 Bu = *(const short8*)(H + rbase + offBu);

            // residual acc starts now: br + h (identity MFMA on the idle pipe)
            float4v r0 = BRv[0], r1 = BRv[1];
            r0 = __builtin_amdgcn_mfma_f32_16x16x32_bf16(I0, Bu, r0, 0, 0, 0);
            r1 = __builtin_amdgcn_mfma_f32_16x16x32_bf16(I1, Bu, r1, 0, 0, 0);

            float4v a0 = BDv[0], a1 = BDv[1], a2 = BDv[2], a3 = BDv[3];
            a0 = __builtin_amdgcn_mfma_f32_16x16x32_bf16(WA[0][0], Bs, a0, 0, 0, 0);
            a0 = __builtin_amdgcn_mfma_f32_16x16x32_bf16(WA[0][1], Bu, a0, 0, 0, 0);
            a1 = __builtin_amdgcn_mfma_f32_16x16x32_bf16(WA[1][0], Bs, a1, 0, 0, 0);
            a1 = __builtin_amdgcn_mfma_f32_16x16x32_bf16(WA[1][1], Bu, a1, 0, 0, 0);
            a2 = __builtin_amdgcn_mfma_f32_16x16x32_bf16(WA[2][0], Bs, a2, 0, 0, 0);
            a2 = __builtin_amdgcn_mfma_f32_16x16x32_bf16(WA[2][1], Bu, a2, 0, 0, 0);
            a3 = __builtin_amdgcn_mfma_f32_16x16x32_bf16(WA[3][0], Bs, a3, 0, 0, 0);
            a3 = __builtin_amdgcn_mfma_f32_16x16x32_bf16(WA[3][1], Bu, a3, 0, 0, 0);

            // gates with paired reciprocals (acc holds pre-scaled exp2 args)
            float g00, g01, g02, g03, g10, g11, g12, g13;
            gate_pair(a0[0], a2[0], a0[1], a2[1], g00, g01);
            gate_pair(a0[2], a2[2], a0[3], a2[3], g02, g03);
            gate_pair(a1[0], a3[0], a1[1], a3[1], g10, g11);
            gate_pair(a1[2], a3[2], a1[3], a3[3], g12, g13);
            int P0 = (int)pk_rne(g00, g01), P1 = (int)pk_rne(g02, g03);
            int P2 = (int)pk_rne(g10, g11), P3 = (int)pk_rne(g12, g13);

            int A0 = __builtin_amdgcn_ds_bpermute(adr1, P0);
            int A1 = __builtin_amdgcn_ds_bpermute(adr1, P1);
            int A2 = __builtin_amdgcn_ds_bpermute(adr1, P2);
            int A3 = __builtin_amdgcn_ds_bpermute(adr1, P3);
            int C0 = __builtin_amdgcn_ds_bpermute(adr2, P0);
            int C1 = __builtin_amdgcn_ds_bpermute(adr2, P1);
            int C2 = __builtin_amdgcn_ds_bpermute(adr2, P2);
            int C3 = __builtin_amdgcn_ds_bpermute(adr2, P3);
            union { int i[4]; short8 v; } ug;
            ug.i[0] = hi ? A2 : A0; ug.i[1] = hi ? A3 : A1;
            ug.i[2] = hi ? C2 : C0; ug.i[3] = hi ? C3 : C1;
            const short8 Gf = ug.v;

            r0 = __builtin_amdgcn_mfma_f32_16x16x32_bf16(WR[0], Gf, r0, 0, 0, 0);
            r1 = __builtin_amdgcn_mfma_f32_16x16x32_bf16(WR[1], Gf, r1, 0, 0, 0);

            n0 = (uint2v){pk_rne(r0[0], r0[1]), pk_rne(r0[2], r0[3])};
            n1 = (uint2v){pk_rne(r1[0], r1[1]), pk_rne(r1[2], r1[3])};
        };
        auto store_tile = [&](int s, const uint2v& n0, const uint2v& n1) {
            const int rbase = (rowu0 + s * (NWAVE * 16)) * 32;
            *(uint2v*)(H + rbase + offH1) = n0;
            *(uint2v*)(H + rbase + offH2) = n1;
        };

        // In-place update, descending two-pass. Tiles = wave + 8*slot.
        // Pass A: slots 3..6 (tiles 24..48, writes rows >= PADT+384); pass B:
        // slots 0..2 (tiles 0..23, reads rows <= PADT+383) -> storeA overlaps
        // computeB with no barrier (disjoint row ranges).
        uint2v A0v[4], A1v[4], B0v[3], B1v[3];
        do_tile(3, A0v[0], A1v[0]);
        do_tile(4, A0v[1], A1v[1]);
        do_tile(5, A0v[2], A1v[2]);
        if (wave == 0) do_tile(6, A0v[3], A1v[3]);   // tile 48 (wave-uniform branch)
        __syncthreads();                         // pass-A reads done
        store_tile(3, A0v[0], A1v[0]);
        store_tile(4, A0v[1], A1v[1]);
        store_tile(5, A0v[2], A1v[2]);
        if (wave == 0) store_tile(6, A0v[3], A1v[3]);
        // no barrier: pass-B reads never touch pass-A rows
        do_tile(0, B0v[0], B1v[0]);
        do_tile(1, B0v[1], B1v[1]);
        do_tile(2, B0v[2], B1v[2]);
        __syncthreads();                         // pass-B reads + pass-A writes done
        store_tile(0, B0v[0], B1v[0]);
        store_tile(1, B0v[1], B1v[1]);
        store_tile(2, B0v[2], B1v[2]);
        __syncthreads();                         // writes visible for next layer
    }

    // ---- output proj ----
    {
        float wo[32];
        #pragma unroll
        for (int k = 0; k < 32; ++k) wo[k] = w_out[k];
        float bo = b_out[0];
        for (int t = tid; t < SEQ; t += BLK) {
            int r = PADT + t;
            int sw = ((r >> 1) & 3) << 3;
            const unsigned short* hp = H + r * 32;
            float s = bo;
            #pragma unroll
            for (int kk = 0; kk < 32; kk += 4) {
                int c = ((((kk >> 3) << 3) ^ sw)) + (kk & 7);
                uint2v hh = *(const uint2v*)(hp + c);
                s += wo[kk]     * __uint_as_float(hh.x << 16);
                s += wo[kk + 1] * __uint_as_float(hh.x & 0xffff0000u);
                s += wo[kk + 2] * __uint_as_float(hh.y << 16);
                s += wo[kk + 3] * __uint_as_float(hh.y & 0xffff0000u);
            }
            out[b * SEQ + t] = s;
        }
    }
}

extern "C" void kernel_launch(void* const* d_in, const int* in_sizes, int n_in,
                              void* d_out, int out_size, void* d_ws, size_t ws_size,
                              hipStream_t stream) {
    const float* x        = (const float*)d_in[0];
    const float* w_causal = (const float*)d_in[1];
    const float* b_causal = (const float*)d_in[2];
    const float* w_dil    = (const float*)d_in[3];
    const float* b_dil    = (const float*)d_in[4];
    const float* w_res    = (const float*)d_in[5];
    const float* b_res    = (const float*)d_in[6];
    const float* w_out    = (const float*)d_in[7];
    const float* b_out    = (const float*)d_in[8];
    float* out = (float*)d_out;
    unsigned char* ws = (unsigned char*)d_ws;

    const int B = in_sizes[0] / SEQ;  // 2048

    prep_kernel<<<10, 64, 0, stream>>>(w_dil, b_dil, w_res, ws);
    wavenet_kernel<<<B, BLK, LDS_BYTES, stream>>>(
        x, w_causal, b_causal, b_res, w_out, b_out, ws, out);
}